// Round 1
// baseline (3757.087 us; speedup 1.0000x reference)
//
#include <hip/hip_runtime.h>
#include <math.h>

#define H    1024
#define C    151
#define E    200
#define DIN  2048
#define T    32
#define B    128
#define SIXH  (6*H)   // 6144
#define FIVEH (5*H)   // 5120
#define KTOT  DIN     // 2048
#define NEMB  (C+1)   // 152

// ---------------- init: zero h, c, eidx=0 ----------------
__global__ void init_kernel(float* h, float* c, int* eidx) {
    int i = blockIdx.x * blockDim.x + threadIdx.x;
    if (i < B * H) { h[i] = 0.f; c[i] = 0.f; }
    if (i < B) eidx[i] = 0;
}

// ---------------- Etab[k][n] = sum_e embed[k][e] * Wi[DIN+e][n] ----------------
// grid (SIXH/256, NEMB), 256 threads
__global__ void etab_kernel(const float* __restrict__ embed,
                            const float* __restrict__ Wi,
                            float* __restrict__ Etab) {
    int n = blockIdx.x * 256 + threadIdx.x;
    int k = blockIdx.y;
    const float* wp = Wi + (size_t)DIN * SIXH + n;
    const float* ep = embed + k * E;
    float acc = 0.f;
    #pragma unroll 8
    for (int e = 0; e < E; ++e)
        acc = fmaf(ep[e], wp[(size_t)e * SIXH], acc);
    Etab[(size_t)k * SIXH + n] = acc;
}

// ---------------- P = X @ Wi_x + bi   [4096, 6144], fp32 tiled ----------------
// BM=128 BN=128 BK=16, 256 threads, 8x8 per thread. grid (SIXH/128, 4096/128)
__launch_bounds__(256, 2)
__global__ void big_gemm(const float* __restrict__ X,
                         const float* __restrict__ Wi,
                         const float* __restrict__ bi,
                         float* __restrict__ P) {
    __shared__ float As[16][128];
    __shared__ float Bs[16][128];
    int tid = threadIdx.x;
    int n0 = blockIdx.x * 128;
    int m0 = blockIdx.y * 128;
    int tm = (tid / 16) * 8;
    int tn = (tid % 16) * 8;
    float acc[8][8] = {};
    for (int k0 = 0; k0 < KTOT; k0 += 16) {
        #pragma unroll
        for (int i = 0; i < 2; ++i) {
            int f = tid + i * 256;
            int row = f >> 2;            // 0..127
            int c4  = (f & 3) * 4;       // 0,4,8,12
            float4 v = *(const float4*)(X + (size_t)(m0 + row) * KTOT + k0 + c4);
            As[c4 + 0][row] = v.x;
            As[c4 + 1][row] = v.y;
            As[c4 + 2][row] = v.z;
            As[c4 + 3][row] = v.w;
        }
        #pragma unroll
        for (int i = 0; i < 2; ++i) {
            int f = tid + i * 256;
            int row = f >> 5;            // 0..15
            int c4  = (f & 31) * 4;
            *(float4*)&Bs[row][c4] =
                *(const float4*)(Wi + (size_t)(k0 + row) * SIXH + n0 + c4);
        }
        __syncthreads();
        #pragma unroll
        for (int k = 0; k < 16; ++k) {
            float a[8], b[8];
            *(float4*)&a[0] = *(const float4*)&As[k][tm];
            *(float4*)&a[4] = *(const float4*)&As[k][tm + 4];
            *(float4*)&b[0] = *(const float4*)&Bs[k][tn];
            *(float4*)&b[4] = *(const float4*)&Bs[k][tn + 4];
            #pragma unroll
            for (int i = 0; i < 8; ++i)
                #pragma unroll
                for (int j = 0; j < 8; ++j)
                    acc[i][j] = fmaf(a[i], b[j], acc[i][j]);
        }
        __syncthreads();
    }
    #pragma unroll
    for (int i = 0; i < 8; ++i) {
        float* pr = P + (size_t)(m0 + tm + i) * SIXH + n0 + tn;
        #pragma unroll
        for (int j = 0; j < 8; ++j)
            pr[j] = acc[i][j] + bi[n0 + tn + j];
    }
}

// ---------------- ps_part[s][b][n] partial of h @ Ws, K split by 8 ----------------
// grid (FIVEH/32, 8), 256 threads. BM=128(all batch) BN=32 BK=32, 8x2 per thread.
__launch_bounds__(256, 4)
__global__ void ps_gemm(const float* __restrict__ h,
                        const float* __restrict__ Ws,
                        float* __restrict__ ps_part) {
    __shared__ float Hs[32][128];
    __shared__ float Wss[32][32];
    int tid = threadIdx.x;
    int n0 = blockIdx.x * 32;
    int ks = blockIdx.y;          // 0..7, K range 128
    int tb = (tid / 16) * 8;
    int tn = (tid % 16) * 2;
    float acc[8][2] = {};
    for (int it = 0; it < 4; ++it) {
        int k0 = ks * 128 + it * 32;
        #pragma unroll
        for (int i = 0; i < 4; ++i) {
            int f = tid + i * 256;
            int b  = f >> 3;          // 0..127
            int c4 = (f & 7) * 4;     // 0..28
            float4 v = *(const float4*)(h + b * H + k0 + c4);
            Hs[c4 + 0][b] = v.x;
            Hs[c4 + 1][b] = v.y;
            Hs[c4 + 2][b] = v.z;
            Hs[c4 + 3][b] = v.w;
        }
        {
            int r  = tid >> 3;        // 0..31
            int c4 = (tid & 7) * 4;
            *(float4*)&Wss[r][c4] =
                *(const float4*)(Ws + (size_t)(k0 + r) * FIVEH + n0 + c4);
        }
        __syncthreads();
        #pragma unroll
        for (int k = 0; k < 32; ++k) {
            float a[8];
            *(float4*)&a[0] = *(const float4*)&Hs[k][tb];
            *(float4*)&a[4] = *(const float4*)&Hs[k][tb + 4];
            float b0 = Wss[k][tn];
            float b1 = Wss[k][tn + 1];
            #pragma unroll
            for (int i = 0; i < 8; ++i) {
                acc[i][0] = fmaf(a[i], b0, acc[i][0]);
                acc[i][1] = fmaf(a[i], b1, acc[i][1]);
            }
        }
        __syncthreads();
    }
    float* out = ps_part + ((size_t)ks * B + tb) * FIVEH + n0 + tn;
    #pragma unroll
    for (int i = 0; i < 8; ++i) {
        out[0] = acc[i][0];
        out[1] = acc[i][1];
        out += FIVEH;
    }
}

// ---------------- gates + LSTM/highway state update ----------------
// grid (H/256, B), 256 threads
__global__ void gate_kernel(const float* __restrict__ P,
                            const float* __restrict__ Etab,
                            const float* __restrict__ ps_part,
                            const float* __restrict__ bs,
                            const int* __restrict__ eidx,
                            float* __restrict__ h,
                            float* __restrict__ c,
                            int t) {
    int j = blockIdx.x * 256 + threadIdx.x;   // 0..H-1
    int b = blockIdx.y;
    const float* prow = P + (size_t)(t * B + b) * SIXH;
    const float* erow = Etab + (size_t)eidx[b] * SIXH;
    float g[5];
    #pragma unroll
    for (int k = 0; k < 5; ++k) {
        int col = k * H + j;
        float ps = bs[col];
        #pragma unroll
        for (int s = 0; s < 8; ++s)
            ps += ps_part[((size_t)s * B + b) * FIVEH + col];
        g[k] = prow[col] + erow[col] + ps;
    }
    float pi5 = prow[5 * H + j] + erow[5 * H + j];
    float ig = 1.f / (1.f + expf(-g[0]));
    float fg = 1.f / (1.f + expf(-g[1]));
    float mi = tanhf(g[2]);
    float og = 1.f / (1.f + expf(-g[3]));
    float hw = 1.f / (1.f + expf(-g[4]));
    float cv = c[b * H + j];
    float cn = ig * mi + fg * cv;
    float out = og * tanhf(cn);
    float hn = hw * out + (1.f - hw) * pi5;
    c[b * H + j] = cn;
    h[b * H + j] = hn;
}

// ---------------- pred = h @ Wo + bo, argmax feedback, write outputs ----------------
// grid (B), 256 threads
__global__ void pred_kernel(const float* __restrict__ h,
                            const float* __restrict__ Wo,
                            const float* __restrict__ bo,
                            const int* __restrict__ labels,
                            float* __restrict__ dists,
                            float* __restrict__ comms,
                            int* __restrict__ eidx,
                            int t) {
    __shared__ float hs[H];
    __shared__ float vals[256];
    __shared__ int   idxs[256];
    int tid = threadIdx.x;
    int b = blockIdx.x;
    for (int i = tid; i < H / 4; i += 256)
        *(float4*)&hs[i * 4] = *(const float4*)&h[b * H + i * 4];
    __syncthreads();
    float pred = 0.f;
    if (tid < C) {
        pred = bo[tid];
        #pragma unroll 8
        for (int k = 0; k < H; ++k)
            pred = fmaf(hs[k], Wo[k * C + tid], pred);
        dists[(size_t)(t * B + b) * C + tid] = pred;
    }
    vals[tid] = (tid >= 1 && tid < C) ? pred : -1e30f;
    idxs[tid] = tid;
    __syncthreads();
    for (int s = 128; s > 0; s >>= 1) {
        if (tid < s) {
            float v2 = vals[tid + s];
            int   i2 = idxs[tid + s];
            if (v2 > vals[tid] || (v2 == vals[tid] && i2 < idxs[tid])) {
                vals[tid] = v2;
                idxs[tid] = i2;
            }
        }
        __syncthreads();
    }
    if (tid == 0) {
        int nzp = idxs[0];                    // class index in 1..150 (first max)
        int lt = labels[t * B + b];
        int comm = (lt == 0) ? nzp : lt;
        comms[t * B + b] = (float)comm;
        eidx[b] = comm + 1;                   // embed[l2e + 1]
    }
}

extern "C" void kernel_launch(void* const* d_in, const int* in_sizes, int n_in,
                              void* d_out, int out_size, void* d_ws, size_t ws_size,
                              hipStream_t stream) {
    const float* X      = (const float*)d_in[0];
    const int*   labels = (const int*)  d_in[1];
    const float* embed  = (const float*)d_in[2];
    const float* Wi     = (const float*)d_in[3];
    const float* bi     = (const float*)d_in[4];
    const float* Ws     = (const float*)d_in[5];
    const float* bs     = (const float*)d_in[6];
    const float* Wo     = (const float*)d_in[7];
    const float* bo     = (const float*)d_in[8];

    float* ws      = (float*)d_ws;
    float* P       = ws;                                  // [T*B][6H]  25,165,824 f
    float* Etab    = P + (size_t)T * B * SIXH;            // [152][6H]     933,888 f
    float* ps_part = Etab + (size_t)NEMB * SIXH;          // [8][B][5H]  5,242,880 f
    float* h       = ps_part + (size_t)8 * B * FIVEH;     // [B][H]
    float* c       = h + (size_t)B * H;                   // [B][H]
    int*   eidx    = (int*)(c + (size_t)B * H);           // [B]

    float* dists = (float*)d_out;
    float* comms = dists + (size_t)T * B * C;

    init_kernel<<<(B * H + 255) / 256, 256, 0, stream>>>(h, c, eidx);
    etab_kernel<<<dim3(SIXH / 256, NEMB), 256, 0, stream>>>(embed, Wi, Etab);
    big_gemm<<<dim3(SIXH / 128, (T * B) / 128), 256, 0, stream>>>(X, Wi, bi, P);

    for (int t = 0; t < T; ++t) {
        ps_gemm<<<dim3(FIVEH / 32, 8), 256, 0, stream>>>(h, Ws, ps_part);
        gate_kernel<<<dim3(H / 256, B), 256, 0, stream>>>(P, Etab, ps_part, bs, eidx, h, c, t);
        pred_kernel<<<B, 256, 0, stream>>>(h, Wo, bo, labels, dists, comms, eidx, t);
    }
}

// Round 2
// 2561.062 us; speedup vs baseline: 1.4670x; 1.4670x over previous
//
#include <hip/hip_runtime.h>
#include <math.h>

#define H    1024
#define C    151
#define E    200
#define DIN  2048
#define T    32
#define B    128
#define SIXH  (6*H)   // 6144
#define FIVEH (5*H)   // 5120
#define KTOT  DIN     // 2048
#define NEMB  (C+1)   // 152

typedef _Float16 f16x8 __attribute__((ext_vector_type(8)));
typedef _Float16 f16x4 __attribute__((ext_vector_type(4)));
typedef float    f32x4 __attribute__((ext_vector_type(4)));

#define GLOAD_LDS16(g, l) __builtin_amdgcn_global_load_lds( \
    (const __attribute__((address_space(1))) unsigned int*)(g), \
    (__attribute__((address_space(3))) unsigned int*)(l), 16, 0, 0)

// ---------------- init: zero h, c, hhi, hlo, eidx ----------------
__global__ void init_kernel(float* h, float* c, _Float16* hhi, _Float16* hlo, int* eidx) {
    int i = blockIdx.x * blockDim.x + threadIdx.x;
    if (i < B * H) {
        h[i] = 0.f; c[i] = 0.f;
        hhi[i] = (_Float16)0.f; hlo[i] = (_Float16)0.f;
    }
    if (i < B) eidx[i] = 0;
}

// ---------------- X [4096][2048] fp32 -> hi/lo fp16 (same layout) ----------------
__global__ void cvt_x(const float* __restrict__ X, _Float16* __restrict__ hi,
                      _Float16* __restrict__ lo) {
    size_t i = ((size_t)blockIdx.x * 256 + threadIdx.x) * 4;
    float4 v = *(const float4*)(X + i);
    f16x4 h, l;
    h.x = (_Float16)v.x; l.x = (_Float16)(v.x - (float)h.x);
    h.y = (_Float16)v.y; l.y = (_Float16)(v.y - (float)h.y);
    h.z = (_Float16)v.z; l.z = (_Float16)(v.z - (float)h.z);
    h.w = (_Float16)v.w; l.w = (_Float16)(v.w - (float)h.w);
    *(f16x4*)(hi + i) = h;
    *(f16x4*)(lo + i) = l;
}

// ---------------- W [KR][NC] fp32 -> out [NC][KR] hi/lo fp16 (transposed) ----------------
template<int KR, int NC>
__global__ void cvt_wT(const float* __restrict__ W, _Float16* __restrict__ hi,
                       _Float16* __restrict__ lo) {
    __shared__ float tile[32][33];
    int n0 = blockIdx.x * 32, k0 = blockIdx.y * 32;
    int tx = threadIdx.x & 31, ty = threadIdx.x >> 5;   // ty 0..7
    #pragma unroll
    for (int i = 0; i < 4; ++i) {
        int k = ty + i * 8;
        tile[k][tx] = W[(size_t)(k0 + k) * NC + n0 + tx];
    }
    __syncthreads();
    #pragma unroll
    for (int i = 0; i < 4; ++i) {
        int n = ty + i * 8;
        float v = tile[tx][n];              // = W[k0+tx][n0+n]
        _Float16 h = (_Float16)v;
        size_t o = (size_t)(n0 + n) * KR + k0 + tx;
        hi[o] = h;
        lo[o] = (_Float16)(v - (float)h);
    }
}

// ---------------- Etab[k][n] = sum_e embed[k][e] * Wi[DIN+e][n]  (fp32) ----------------
__global__ void etab_kernel(const float* __restrict__ embed,
                            const float* __restrict__ Wi,
                            float* __restrict__ Etab) {
    int n = blockIdx.x * 256 + threadIdx.x;
    int k = blockIdx.y;
    const float* wp = Wi + (size_t)DIN * SIXH + n;
    const float* ep = embed + k * E;
    float acc = 0.f;
    #pragma unroll 8
    for (int e = 0; e < E; ++e)
        acc = fmaf(ep[e], wp[(size_t)e * SIXH], acc);
    Etab[(size_t)k * SIXH + n] = acc;
}

// ---------------- P = X @ Wi_x + bi, fp16x3 MFMA. tile 128x128, 4 waves x 64x64 ----------
// A = Xhi/Xlo [4096][2048] (k-contig). B = WiT hi/lo [6144][2048] (k-contig).
__global__ __launch_bounds__(256) void big_gemm_mfma(
    const _Float16* __restrict__ Ahi, const _Float16* __restrict__ Alo,
    const _Float16* __restrict__ Bhi, const _Float16* __restrict__ Blo,
    const float* __restrict__ bi, float* __restrict__ P)
{
    __shared__ __align__(16) _Float16 sAh[128 * 32];
    __shared__ __align__(16) _Float16 sAl[128 * 32];
    __shared__ __align__(16) _Float16 sBh[128 * 32];
    __shared__ __align__(16) _Float16 sBl[128 * 32];
    const int tid = threadIdx.x;
    const int n0 = blockIdx.x * 128;
    const int m0 = blockIdx.y * 128;
    const int lane = tid & 63, w = tid >> 6;
    const int wm = (w >> 1) * 64, wn = (w & 1) * 64;
    const int lr = lane & 15, lq = lane >> 4;

    f32x4 acc[4][4];
    #pragma unroll
    for (int i = 0; i < 4; ++i)
        #pragma unroll
        for (int j = 0; j < 4; ++j)
            acc[i][j] = (f32x4){0.f, 0.f, 0.f, 0.f};

    const int row0 = tid >> 2;        // 0..63
    const int kc = tid & 3;

    for (int k0 = 0; k0 < KTOT; k0 += 32) {
        #pragma unroll
        for (int i = 0; i < 2; ++i) {
            int row = row0 + i * 64;
            size_t ga = (size_t)(m0 + row) * KTOT + k0 + kc * 8;
            size_t gb = (size_t)(n0 + row) * KTOT + k0 + kc * 8;
            int loff = (i * 256 + tid) * 8;        // halves
            GLOAD_LDS16(Ahi + ga, sAh + loff);
            GLOAD_LDS16(Alo + ga, sAl + loff);
            GLOAD_LDS16(Bhi + gb, sBh + loff);
            GLOAD_LDS16(Blo + gb, sBl + loff);
        }
        __syncthreads();
        f16x8 ah[4], al[4], bh[4], bl[4];
        #pragma unroll
        for (int i = 0; i < 4; ++i) {
            ah[i] = *(const f16x8*)&sAh[(wm + i * 16 + lr) * 32 + lq * 8];
            al[i] = *(const f16x8*)&sAl[(wm + i * 16 + lr) * 32 + lq * 8];
            bh[i] = *(const f16x8*)&sBh[(wn + i * 16 + lr) * 32 + lq * 8];
            bl[i] = *(const f16x8*)&sBl[(wn + i * 16 + lr) * 32 + lq * 8];
        }
        #pragma unroll
        for (int i = 0; i < 4; ++i)
            #pragma unroll
            for (int j = 0; j < 4; ++j) {
                acc[i][j] = __builtin_amdgcn_mfma_f32_16x16x32_f16(ah[i], bh[j], acc[i][j], 0, 0, 0);
                acc[i][j] = __builtin_amdgcn_mfma_f32_16x16x32_f16(ah[i], bl[j], acc[i][j], 0, 0, 0);
                acc[i][j] = __builtin_amdgcn_mfma_f32_16x16x32_f16(al[i], bh[j], acc[i][j], 0, 0, 0);
            }
        __syncthreads();
    }
    #pragma unroll
    for (int i = 0; i < 4; ++i)
        #pragma unroll
        for (int j = 0; j < 4; ++j) {
            int gcol = n0 + wn + j * 16 + lr;
            float bv = bi[gcol];
            #pragma unroll
            for (int r = 0; r < 4; ++r) {
                int grow = m0 + wm + i * 16 + lq * 4 + r;
                P[(size_t)grow * SIXH + gcol] = acc[i][j][r] + bv;
            }
        }
}

// ---------------- ps = h @ Ws, fp16x3 MFMA. tile 64x64, 4 waves x 32x32 ----------------
// A = hhi/hlo [128][1024]. B = WsT hi/lo [5120][1024]. grid (5120/64, 128/64)
__global__ __launch_bounds__(256) void ps_mfma(
    const _Float16* __restrict__ Ahi, const _Float16* __restrict__ Alo,
    const _Float16* __restrict__ Bhi, const _Float16* __restrict__ Blo,
    float* __restrict__ ps)
{
    __shared__ __align__(16) _Float16 sAh[64 * 32];
    __shared__ __align__(16) _Float16 sAl[64 * 32];
    __shared__ __align__(16) _Float16 sBh[64 * 32];
    __shared__ __align__(16) _Float16 sBl[64 * 32];
    const int tid = threadIdx.x;
    const int n0 = blockIdx.x * 64;
    const int m0 = blockIdx.y * 64;
    const int lane = tid & 63, w = tid >> 6;
    const int wm = (w >> 1) * 32, wn = (w & 1) * 32;
    const int lr = lane & 15, lq = lane >> 4;

    f32x4 acc[2][2];
    #pragma unroll
    for (int i = 0; i < 2; ++i)
        #pragma unroll
        for (int j = 0; j < 2; ++j)
            acc[i][j] = (f32x4){0.f, 0.f, 0.f, 0.f};

    const int row = tid >> 2;     // 0..63
    const int kc = tid & 3;

    for (int k0 = 0; k0 < H; k0 += 32) {
        size_t ga = (size_t)(m0 + row) * H + k0 + kc * 8;
        size_t gb = (size_t)(n0 + row) * H + k0 + kc * 8;
        int loff = tid * 8;
        GLOAD_LDS16(Ahi + ga, sAh + loff);
        GLOAD_LDS16(Alo + ga, sAl + loff);
        GLOAD_LDS16(Bhi + gb, sBh + loff);
        GLOAD_LDS16(Blo + gb, sBl + loff);
        __syncthreads();
        f16x8 ah[2], al[2], bh[2], bl[2];
        #pragma unroll
        for (int i = 0; i < 2; ++i) {
            ah[i] = *(const f16x8*)&sAh[(wm + i * 16 + lr) * 32 + lq * 8];
            al[i] = *(const f16x8*)&sAl[(wm + i * 16 + lr) * 32 + lq * 8];
            bh[i] = *(const f16x8*)&sBh[(wn + i * 16 + lr) * 32 + lq * 8];
            bl[i] = *(const f16x8*)&sBl[(wn + i * 16 + lr) * 32 + lq * 8];
        }
        #pragma unroll
        for (int i = 0; i < 2; ++i)
            #pragma unroll
            for (int j = 0; j < 2; ++j) {
                acc[i][j] = __builtin_amdgcn_mfma_f32_16x16x32_f16(ah[i], bh[j], acc[i][j], 0, 0, 0);
                acc[i][j] = __builtin_amdgcn_mfma_f32_16x16x32_f16(ah[i], bl[j], acc[i][j], 0, 0, 0);
                acc[i][j] = __builtin_amdgcn_mfma_f32_16x16x32_f16(al[i], bh[j], acc[i][j], 0, 0, 0);
            }
        __syncthreads();
    }
    #pragma unroll
    for (int i = 0; i < 2; ++i)
        #pragma unroll
        for (int j = 0; j < 2; ++j) {
            int gcol = n0 + wn + j * 16 + lr;
            #pragma unroll
            for (int r = 0; r < 4; ++r) {
                int grow = m0 + wm + i * 16 + lq * 4 + r;
                ps[(size_t)grow * FIVEH + gcol] = acc[i][j][r];
            }
        }
}

// ---------------- gates + LSTM/highway; also emits hhi/hlo for next ps ----------------
__global__ void gate_kernel(const float* __restrict__ P,
                            const float* __restrict__ Etab,
                            const float* __restrict__ ps,
                            const float* __restrict__ bs,
                            const int* __restrict__ eidx,
                            float* __restrict__ h,
                            float* __restrict__ c,
                            _Float16* __restrict__ hhi,
                            _Float16* __restrict__ hlo,
                            int t) {
    int j = blockIdx.x * 256 + threadIdx.x;   // 0..H-1
    int b = blockIdx.y;
    const float* prow = P + (size_t)(t * B + b) * SIXH;
    const float* erow = Etab + (size_t)eidx[b] * SIXH;
    const float* psr  = ps + (size_t)b * FIVEH;
    float g[5];
    #pragma unroll
    for (int k = 0; k < 5; ++k) {
        int col = k * H + j;
        g[k] = prow[col] + erow[col] + psr[col] + bs[col];
    }
    float pi5 = prow[5 * H + j] + erow[5 * H + j];
    float ig = 1.f / (1.f + expf(-g[0]));
    float fg = 1.f / (1.f + expf(-g[1]));
    float mi = tanhf(g[2]);
    float og = 1.f / (1.f + expf(-g[3]));
    float hw = 1.f / (1.f + expf(-g[4]));
    float cv = c[b * H + j];
    float cn = ig * mi + fg * cv;
    float out = og * tanhf(cn);
    float hn = hw * out + (1.f - hw) * pi5;
    c[b * H + j] = cn;
    h[b * H + j] = hn;
    _Float16 hh = (_Float16)hn;
    hhi[b * H + j] = hh;
    hlo[b * H + j] = (_Float16)(hn - (float)hh);
}

// ---------------- pred = h @ Wo + bo, argmax feedback, write outputs ----------------
__global__ void pred_kernel(const float* __restrict__ h,
                            const float* __restrict__ Wo,
                            const float* __restrict__ bo,
                            const int* __restrict__ labels,
                            float* __restrict__ dists,
                            float* __restrict__ comms,
                            int* __restrict__ eidx,
                            int t) {
    __shared__ float hs[H];
    __shared__ float vals[256];
    __shared__ int   idxs[256];
    int tid = threadIdx.x;
    int b = blockIdx.x;
    for (int i = tid; i < H / 4; i += 256)
        *(float4*)&hs[i * 4] = *(const float4*)&h[b * H + i * 4];
    __syncthreads();
    float pred = 0.f;
    if (tid < C) {
        pred = bo[tid];
        #pragma unroll 8
        for (int k = 0; k < H; ++k)
            pred = fmaf(hs[k], Wo[k * C + tid], pred);
        dists[(size_t)(t * B + b) * C + tid] = pred;
    }
    vals[tid] = (tid >= 1 && tid < C) ? pred : -1e30f;
    idxs[tid] = tid;
    __syncthreads();
    for (int s = 128; s > 0; s >>= 1) {
        if (tid < s) {
            float v2 = vals[tid + s];
            int   i2 = idxs[tid + s];
            if (v2 > vals[tid] || (v2 == vals[tid] && i2 < idxs[tid])) {
                vals[tid] = v2;
                idxs[tid] = i2;
            }
        }
        __syncthreads();
    }
    if (tid == 0) {
        int nzp = idxs[0];
        int lt = labels[t * B + b];
        int comm = (lt == 0) ? nzp : lt;
        comms[t * B + b] = (float)comm;
        eidx[b] = comm + 1;
    }
}

extern "C" void kernel_launch(void* const* d_in, const int* in_sizes, int n_in,
                              void* d_out, int out_size, void* d_ws, size_t ws_size,
                              hipStream_t stream) {
    const float* X      = (const float*)d_in[0];
    const int*   labels = (const int*)  d_in[1];
    const float* embed  = (const float*)d_in[2];
    const float* Wi     = (const float*)d_in[3];
    const float* bi     = (const float*)d_in[4];
    const float* Ws     = (const float*)d_in[5];
    const float* bs     = (const float*)d_in[6];
    const float* Wo     = (const float*)d_in[7];
    const float* bo     = (const float*)d_in[8];

    char* w = (char*)d_ws;
    float* P      = (float*)w;              w += (size_t)T * B * SIXH * 4;      // 100.7 MB
    float* Etab   = (float*)w;              w += (size_t)NEMB * SIXH * 4;       //   3.7 MB
    float* ps     = (float*)w;              w += (size_t)B * FIVEH * 4;         //   2.6 MB
    float* h      = (float*)w;              w += (size_t)B * H * 4;
    float* c      = (float*)w;              w += (size_t)B * H * 4;
    _Float16* hhi = (_Float16*)w;           w += (size_t)B * H * 2;
    _Float16* hlo = (_Float16*)w;           w += (size_t)B * H * 2;
    int* eidx     = (int*)w;                w += 512;
    _Float16* Xhi = (_Float16*)w;           w += (size_t)T * B * KTOT * 2;      //  16.8 MB
    _Float16* Xlo = (_Float16*)w;           w += (size_t)T * B * KTOT * 2;
    _Float16* WiThi = (_Float16*)w;         w += (size_t)SIXH * KTOT * 2;       //  25.2 MB
    _Float16* WiTlo = (_Float16*)w;         w += (size_t)SIXH * KTOT * 2;
    _Float16* WsThi = (_Float16*)w;         w += (size_t)FIVEH * H * 2;         //  10.5 MB
    _Float16* WsTlo = (_Float16*)w;         w += (size_t)FIVEH * H * 2;

    float* dists = (float*)d_out;
    float* comms = dists + (size_t)T * B * C;

    init_kernel<<<512, 256, 0, stream>>>(h, c, hhi, hlo, eidx);
    cvt_x<<<(T * B * KTOT) / (256 * 4), 256, 0, stream>>>(X, Xhi, Xlo);
    cvt_wT<KTOT, SIXH><<<dim3(SIXH / 32, KTOT / 32), 256, 0, stream>>>(Wi, WiThi, WiTlo);
    cvt_wT<H, FIVEH><<<dim3(FIVEH / 32, H / 32), 256, 0, stream>>>(Ws, WsThi, WsTlo);
    etab_kernel<<<dim3(SIXH / 256, NEMB), 256, 0, stream>>>(embed, Wi, Etab);
    big_gemm_mfma<<<dim3(SIXH / 128, (T * B) / 128), 256, 0, stream>>>(Xhi, Xlo, WiThi, WiTlo, bi, P);

    for (int t = 0; t < T; ++t) {
        ps_mfma<<<dim3(FIVEH / 64, B / 64), 256, 0, stream>>>(hhi, hlo, WsThi, WsTlo, ps);
        gate_kernel<<<dim3(H / 256, B), 256, 0, stream>>>(P, Etab, ps, bs, eidx, h, c, hhi, hlo, t);
        pred_kernel<<<B, 256, 0, stream>>>(h, Wo, bo, labels, dists, comms, eidx, t);
    }
}